// Round 1
// 807.241 us; speedup vs baseline: 1.1984x; 1.1984x over previous
//
#include <hip/hip_runtime.h>
#include <hip/hip_bf16.h>

// GRU (TF GRUCell), B=2048, T=12, D=512, H=1024, fp32 in/out.
// R6: pre_gemm rebuilt m97-style: x converted to bf16 once (prep), then
// global_load_lds width-16 for BOTH operands (A via inverse-XOR-swizzled
// per-lane source addresses, LDS linear — m173 pattern; read side keeps the
// measured-conflict-free XOR). Bijective XCD-grouping swizzles on pre_gemm
// and both step kernels (grid%8==0). Steps: depth-4 reg prefetch, u stored
// fp16 (was fp32), gate epilogue reads hb (bf16) not h32, out written
// nontemporal. pack/conv/init fused into one prep dispatch.

#define T_SEQ 12
#define BATCH 2048
#define IND 512
#define HID 1024
#define NGATE (2 * HID)  // 2048
#define NPRE (NGATE + HID)

typedef __bf16 bf16x8 __attribute__((ext_vector_type(8)));
typedef __bf16 bf16x4 __attribute__((ext_vector_type(4)));
typedef float floatx4 __attribute__((ext_vector_type(4)));

#define AS1 __attribute__((address_space(1)))
#define AS3 __attribute__((address_space(3)))

__device__ __forceinline__ void gload16(const __bf16* g, __bf16* l) {
  __builtin_amdgcn_global_load_lds((const AS1 void*)g, (AS3 void*)l, 16, 0, 0);
}

__device__ __forceinline__ float fast_sigmoid(float v) {
  v = fminf(30.f, fmaxf(-30.f, v));
  return 1.f / (1.f + __expf(-v));
}
__device__ __forceinline__ float fast_tanh(float v) {
  v = fminf(15.f, fmaxf(-15.f, v));
  float e = __expf(2.f * v);
  return (e - 1.f) / (e + 1.f);
}

// ---- fused prep: weight pack + x fp32->bf16 + h init, one dispatch ----
// blocks [0,2304): pack; [2304,4352): conv x; [4352,6400): init h.
__global__ __launch_bounds__(256) void prep(
    const float* __restrict__ Wg, const float* __restrict__ Wc,
    const float* __restrict__ x, const float* __restrict__ coded,
    __bf16* __restrict__ Bx, __bf16* __restrict__ Bhg, __bf16* __restrict__ Bhc,
    __bf16* __restrict__ xb, float* __restrict__ h32, __bf16* __restrict__ hb) {
  int b = blockIdx.x;
  if (b < 2304) {
    int gid = b * 256 + threadIdx.x;
    int g = gid >> 6, lane = gid & 63;
    const float* W; int ld, row0, ksteps, wid; __bf16* out;
    if (g < 2048)      { W = Wg; ld = NGATE; row0 = 0;   ksteps = 16; wid = g;        out = Bx; }
    else if (g < 3072) { W = Wc; ld = HID;   row0 = 0;   ksteps = 16; wid = g - 2048; out = Bx + (size_t)2048 * 512; }
    else if (g < 7168) { W = Wg; ld = NGATE; row0 = IND; ksteps = 32; wid = g - 3072; out = Bhg; }
    else               { W = Wc; ld = HID;   row0 = IND; ksteps = 32; wid = g - 7168; out = Bhc; }
    int n16 = wid / ksteps, kt = wid - n16 * ksteps;
    int col = n16 * 16 + (lane & 15);
    int k0 = row0 + kt * 32 + (lane >> 4) * 8;
    bf16x8 v;
#pragma unroll
    for (int j = 0; j < 8; ++j) v[j] = (__bf16)W[(size_t)(k0 + j) * ld + col];
    *reinterpret_cast<bf16x8*>(out + (size_t)wid * 512 + lane * 8) = v;
  } else if (b < 4352) {
    int i = (b - 2304) * 256 + threadIdx.x;
    const float4* x4 = (const float4*)x;
    const int n4 = BATCH * T_SEQ * IND / 4;
    for (int k = i; k < n4; k += 2048 * 256) {
      float4 v = x4[k];
      bf16x4 o;
      o[0] = (__bf16)v.x; o[1] = (__bf16)v.y; o[2] = (__bf16)v.z; o[3] = (__bf16)v.w;
      *reinterpret_cast<bf16x4*>(xb + (size_t)k * 4) = o;
    }
  } else {
    int i = (b - 4352) * 256 + threadIdx.x;  // exactly BATCH*HID/4 threads
    float4 v = ((const float4*)coded)[i];
    ((float4*)h32)[i] = v;
    bf16x4 o;
    o[0] = (__bf16)v.x; o[1] = (__bf16)v.y; o[2] = (__bf16)v.z; o[3] = (__bf16)v.w;
    *reinterpret_cast<bf16x4*>(hb + (size_t)i * 4) = o;
  }
}

// ---- Px precompute: 128x128 tile, wave 64x64 (4x4 frags), K=512 ----
// m97-style: global_load_lds for A (xb bf16, source-XOR-swizzled) and B
// (packed, lane-linear). 1-D grid 4608, XCD-grouped so all 24 N-blocks of
// one x-panel share an XCD L2.
__global__ __launch_bounds__(256) void pre_gemm(
    const __bf16* __restrict__ xb, const __bf16* __restrict__ Bx,
    const float* __restrict__ bg, const float* __restrict__ bc,
    __bf16* __restrict__ Pg, __bf16* __restrict__ Pc) {
  __shared__ __bf16 Alds[128 * 64];  // 16 KB, linear [row][64]
  __shared__ __bf16 Blds[8192];      // 16 KB
  const int tid = threadIdx.x, lane = tid & 63, w = tid >> 6;
  const int wm = w >> 1, wn = w & 1, quad = lane >> 4, l16 = lane & 15;
  const int bid = blockIdx.x;                    // 4608 = 8 * 576
  const int wg = (bid & 7) * 576 + (bid >> 3);   // bijective XCD grouping
  const int nb = wg % 24;
  const int rest = wg / 24;
  const int mB = rest & 15;
  const int tz = rest >> 4;
  const int m0 = mB * 128;

  const __bf16* gA[4]; __bf16* lA[4];
  const __bf16* gB[4]; __bf16* lB[4];
#pragma unroll
  for (int i = 0; i < 4; ++i) {
    int c = tid + i * 256;  // [0,1024): row=c>>3 (0..127), k8=c&7
    int row = c >> 3, k8 = c & 7;
    // inverse swizzle on SOURCE; LDS stays linear; read applies same XOR.
    gA[i] = xb + ((size_t)(m0 + row) * T_SEQ + tz) * IND + ((k8 ^ (row & 7)) * 8);
    lA[i] = Alds + c * 8;
    int ks2c = c >> 9, rem = c & 511;
    gB[i] = Bx + (((size_t)(nb * 8 + (rem >> 6)) * 16 + ks2c) * 64 + (rem & 63)) * 8;
    lB[i] = Blds + c * 8;
  }

  floatx4 acc[4][4] = {};
  for (int it = 0; it < 8; ++it) {
    __syncthreads();
#pragma unroll
    for (int i = 0; i < 4; ++i) gload16(gA[i] + it * 64, lA[i]);
#pragma unroll
    for (int i = 0; i < 4; ++i) gload16(gB[i] + (size_t)it * 1024, lB[i]);
    __syncthreads();
#pragma unroll
    for (int ks2 = 0; ks2 < 2; ++ks2) {
      bf16x8 af[4], bfr[4];
#pragma unroll
      for (int mf = 0; mf < 4; ++mf) {
        int row = wm * 64 + mf * 16 + l16;
        af[mf] = *(const bf16x8*)&Alds[row * 64 + (((ks2 * 4 + quad) ^ (row & 7)) * 8)];
      }
#pragma unroll
      for (int nf = 0; nf < 4; ++nf)
        bfr[nf] = *(const bf16x8*)&Blds[(ks2 * 512 + (wn * 4 + nf) * 64 + lane) * 8];
#pragma unroll
      for (int mf = 0; mf < 4; ++mf)
#pragma unroll
        for (int nf = 0; nf < 4; ++nf)
          acc[mf][nf] = __builtin_amdgcn_mfma_f32_16x16x32_bf16(af[mf], bfr[nf], acc[mf][nf], 0, 0, 0);
    }
  }

  const int n64g = nb * 2 + wn;
  const bool isg = (n64g < 32);
  __bf16* P = isg ? Pg : Pc;
  const float* bias = isg ? bg : bc;
  const int nrel = isg ? n64g : (n64g - 32);
  const int colb = nrel * 64 + l16;
#pragma unroll
  for (int mf = 0; mf < 4; ++mf) {
    int m32 = mB * 4 + wm * 2 + (mf >> 1);
    size_t tb = isg ? (((size_t)tz * 64 + m32) * 32 + n64g) * 2048
                    : (((size_t)tz * 64 + m32) * 16 + nrel) * 2048;
#pragma unroll
    for (int nf = 0; nf < 4; ++nf) {
      float bv = bias[colb + nf * 16];
      bf16x4 st;
#pragma unroll
      for (int i = 0; i < 4; ++i) st[i] = (__bf16)(acc[mf][nf][i] + bv);
      *(bf16x4*)&P[tb + (size_t)(((mf & 1) * 4 + nf) * 64 + lane) * 4] = st;
    }
  }
}

// ---- gate step: 64x128 tile, 4 waves, K=1024, depth-4 reg prefetch ----
__global__ __launch_bounds__(256, 2) void gate_step(
    const __bf16* __restrict__ hb, const __bf16* __restrict__ Bhg,
    const __bf16* __restrict__ Pg, _Float16* __restrict__ u16,
    __bf16* __restrict__ rhb, int t) {
  __shared__ __bf16 Alds[64 * 64];  // 8 KB
  __shared__ __bf16 Blds[8192];     // 16 KB
  const int tid = threadIdx.x, lane = tid & 63, w = tid >> 6;
  const int wm = w >> 1, wn = w & 1, quad = lane >> 4, l16 = lane & 15;
  const int bid = blockIdx.x;                  // 512 = 8 * 64
  const int swz = (bid & 7) * 64 + (bid >> 3); // XCD-grouped: mT panels per XCD
  const int nT = swz & 15, mT = swz >> 4;

  const __bf16* gA[2];
  int ldsA[2];
#pragma unroll
  for (int i = 0; i < 2; ++i) {
    int c = tid + i * 256;  // [0,512): row=c>>3 (0..63), k8=c&7
    gA[i] = hb + (size_t)(mT * 64 + (c >> 3)) * HID + (c & 7) * 8;
    ldsA[i] = (c >> 3) * 64 + (((c & 7) ^ ((c >> 3) & 7)) * 8);
  }
  const __bf16* gB[4];
  int ldsB[4];
#pragma unroll
  for (int i = 0; i < 4; ++i) {
    int c = tid + i * 256;
    int ks2c = c >> 9, rem = c & 511;
    gB[i] = Bhg + (((size_t)(nT * 8 + (rem >> 6)) * 32 + ks2c) * 64 + (rem & 63)) * 8;
    ldsB[i] = c * 8;
  }

  bf16x8 ra[4][2], rb[4][4];
#pragma unroll
  for (int s = 0; s < 4; ++s) {
#pragma unroll
    for (int i = 0; i < 2; ++i) ra[s][i] = *(const bf16x8*)(gA[i] + s * 64);
#pragma unroll
    for (int i = 0; i < 4; ++i) rb[s][i] = *(const bf16x8*)(gB[i] + (size_t)s * 1024);
  }

  floatx4 acc[2][4] = {};
#pragma unroll
  for (int it = 0; it < 16; ++it) {
    const int st = it & 3;
    __syncthreads();
#pragma unroll
    for (int i = 0; i < 2; ++i) *(bf16x8*)&Alds[ldsA[i]] = ra[st][i];
#pragma unroll
    for (int i = 0; i < 4; ++i) *(bf16x8*)&Blds[ldsB[i]] = rb[st][i];
    __syncthreads();
    if (it + 4 < 16) {
#pragma unroll
      for (int i = 0; i < 2; ++i) ra[st][i] = *(const bf16x8*)(gA[i] + (it + 4) * 64);
#pragma unroll
      for (int i = 0; i < 4; ++i) rb[st][i] = *(const bf16x8*)(gB[i] + (size_t)(it + 4) * 1024);
    }
#pragma unroll
    for (int ks2 = 0; ks2 < 2; ++ks2) {
      bf16x8 af[2], bfr[4];
#pragma unroll
      for (int mf = 0; mf < 2; ++mf) {
        int row = wm * 32 + mf * 16 + l16;
        af[mf] = *(const bf16x8*)&Alds[row * 64 + (((ks2 * 4 + quad) ^ (row & 7)) * 8)];
      }
#pragma unroll
      for (int nf = 0; nf < 4; ++nf)
        bfr[nf] = *(const bf16x8*)&Blds[(ks2 * 512 + (wn * 4 + nf) * 64 + lane) * 8];
#pragma unroll
      for (int mf = 0; mf < 2; ++mf)
#pragma unroll
        for (int nf = 0; nf < 4; ++nf)
          acc[mf][nf] = __builtin_amdgcn_mfma_f32_16x16x32_bf16(af[mf], bfr[nf], acc[mf][nf], 0, 0, 0);
    }
  }

  const int m32 = mT * 2 + wm;
  const int n64 = nT * 2 + wn;
  const bool isr = (n64 < 16);
  size_t tb = (((size_t)t * 64 + m32) * 32 + n64) * 2048;
#pragma unroll
  for (int mf = 0; mf < 2; ++mf)
#pragma unroll
    for (int nf = 0; nf < 4; ++nf) {
      bf16x4 px = *(const bf16x4*)&Pg[tb + (size_t)((mf * 4 + nf) * 64 + lane) * 4];
      int col = nT * 128 + wn * 64 + nf * 16 + l16;
      int rowb = mT * 64 + wm * 32 + mf * 16 + quad * 4;
#pragma unroll
      for (int i = 0; i < 4; ++i) {
        float s = fast_sigmoid(acc[mf][nf][i] + (float)px[i]);
        if (isr) {
          size_t idx = (size_t)(rowb + i) * HID + col;
          rhb[idx] = (__bf16)(s * (float)hb[idx]);
        } else {
          u16[(size_t)(rowb + i) * HID + (col - HID)] = (_Float16)s;
        }
      }
    }
}

// ---- cand step: 64x64 tile, 2 waves, K=1024, depth-4 reg prefetch ----
__global__ __launch_bounds__(128, 2) void cand_step(
    const __bf16* __restrict__ rhb, const __bf16* __restrict__ Bhc,
    const __bf16* __restrict__ Pc, const _Float16* __restrict__ u16,
    float* __restrict__ h32, __bf16* __restrict__ hb,
    float* __restrict__ out, int t) {
  __shared__ __bf16 Alds[64 * 64];  // 8 KB
  __shared__ __bf16 Blds[4096];     // 8 KB
  const int tid = threadIdx.x, lane = tid & 63, wm = tid >> 6;
  const int quad = lane >> 4, l16 = lane & 15;
  const int bid = blockIdx.x;                  // 512 = 8 * 64
  const int swz = (bid & 7) * 64 + (bid >> 3);
  const int nT = swz & 15, mT = swz >> 4;

  const __bf16* gA[4];
  int ldsA[4];
#pragma unroll
  for (int i = 0; i < 4; ++i) {
    int c = tid + i * 128;  // [0,512)
    gA[i] = rhb + (size_t)(mT * 64 + (c >> 3)) * HID + (c & 7) * 8;
    ldsA[i] = (c >> 3) * 64 + (((c & 7) ^ ((c >> 3) & 7)) * 8);
  }
  const __bf16* gB[4];
  int ldsB[4];
#pragma unroll
  for (int i = 0; i < 4; ++i) {
    int c = tid + i * 128;  // [0,512)
    int ks2c = c >> 8, rem = c & 255;
    gB[i] = Bhc + (((size_t)(nT * 4 + (rem >> 6)) * 32 + ks2c) * 64 + (rem & 63)) * 8;
    ldsB[i] = c * 8;
  }

  bf16x8 ra[4][4], rb[4][4];
#pragma unroll
  for (int s = 0; s < 4; ++s) {
#pragma unroll
    for (int i = 0; i < 4; ++i) {
      ra[s][i] = *(const bf16x8*)(gA[i] + s * 64);
      rb[s][i] = *(const bf16x8*)(gB[i] + (size_t)s * 1024);
    }
  }

  floatx4 acc[2][4] = {};
#pragma unroll
  for (int it = 0; it < 16; ++it) {
    const int st = it & 3;
    __syncthreads();
#pragma unroll
    for (int i = 0; i < 4; ++i) {
      *(bf16x8*)&Alds[ldsA[i]] = ra[st][i];
      *(bf16x8*)&Blds[ldsB[i]] = rb[st][i];
    }
    __syncthreads();
    if (it + 4 < 16) {
#pragma unroll
      for (int i = 0; i < 4; ++i) {
        ra[st][i] = *(const bf16x8*)(gA[i] + (it + 4) * 64);
        rb[st][i] = *(const bf16x8*)(gB[i] + (size_t)(it + 4) * 1024);
      }
    }
#pragma unroll
    for (int ks2 = 0; ks2 < 2; ++ks2) {
      bf16x8 af[2], bfr[4];
#pragma unroll
      for (int mf = 0; mf < 2; ++mf) {
        int row = wm * 32 + mf * 16 + l16;
        af[mf] = *(const bf16x8*)&Alds[row * 64 + (((ks2 * 4 + quad) ^ (row & 7)) * 8)];
      }
#pragma unroll
      for (int nf = 0; nf < 4; ++nf)
        bfr[nf] = *(const bf16x8*)&Blds[(ks2 * 256 + nf * 64 + lane) * 8];
#pragma unroll
      for (int mf = 0; mf < 2; ++mf)
#pragma unroll
        for (int nf = 0; nf < 4; ++nf)
          acc[mf][nf] = __builtin_amdgcn_mfma_f32_16x16x32_bf16(af[mf], bfr[nf], acc[mf][nf], 0, 0, 0);
    }
  }

  const int m32 = mT * 2 + wm;
  size_t tb = (((size_t)t * 64 + m32) * 16 + nT) * 2048;
#pragma unroll
  for (int mf = 0; mf < 2; ++mf)
#pragma unroll
    for (int nf = 0; nf < 4; ++nf) {
      bf16x4 px = *(const bf16x4*)&Pc[tb + (size_t)((mf * 4 + nf) * 64 + lane) * 4];
      int col = nT * 64 + nf * 16 + l16;
      int rowb = mT * 64 + wm * 32 + mf * 16 + quad * 4;
#pragma unroll
      for (int i = 0; i < 4; ++i) {
        float c = fast_tanh(acc[mf][nf][i] + (float)px[i]);
        size_t idx = (size_t)(rowb + i) * HID + col;
        float u = (float)u16[idx];
        float hnew = u * h32[idx] + (1.f - u) * c;
        h32[idx] = hnew;
        hb[idx] = (__bf16)hnew;
        __builtin_nontemporal_store(hnew, &out[(size_t)(rowb + i) * (T_SEQ * HID) + t * HID + col]);
      }
    }
}

extern "C" void kernel_launch(void* const* d_in, const int* in_sizes, int n_in,
                              void* d_out, int out_size, void* d_ws, size_t ws_size,
                              hipStream_t stream) {
  const float* x     = (const float*)d_in[0];
  const float* coded = (const float*)d_in[1];
  const float* Wg_f  = (const float*)d_in[2];
  const float* bg    = (const float*)d_in[3];
  const float* Wc_f  = (const float*)d_in[4];
  const float* bc    = (const float*)d_in[5];
  float* out = (float*)d_out;

  uintptr_t base = ((uintptr_t)d_ws + 255) & ~(uintptr_t)255;
  auto take = [&](size_t bytes) {
    void* p = (void*)base;
    base = (base + bytes + 255) & ~(uintptr_t)255;
    return p;
  };
  __bf16* Bx  = (__bf16*)take((size_t)(NPRE / 16) * 16 * 512 * 2);   // 3.1 MB
  __bf16* Bhg = (__bf16*)take((size_t)(NGATE / 16) * 32 * 512 * 2);  // 4.2 MB
  __bf16* Bhc = (__bf16*)take((size_t)(HID / 16) * 32 * 512 * 2);    // 2.1 MB
  __bf16* Pg  = (__bf16*)take((size_t)T_SEQ * 64 * 32 * 2048 * 2);   // 100.7 MB
  __bf16* Pc  = (__bf16*)take((size_t)T_SEQ * 64 * 16 * 2048 * 2);   // 50.3 MB
  __bf16* xb  = (__bf16*)take((size_t)BATCH * T_SEQ * IND * 2);      // 25.2 MB
  float*  h32 = (float*) take((size_t)BATCH * HID * 4);
  __bf16* hb  = (__bf16*)take((size_t)BATCH * HID * 2);
  _Float16* u16 = (_Float16*)take((size_t)BATCH * HID * 2);
  __bf16* rhb = (__bf16*)take((size_t)BATCH * HID * 2);

  prep<<<6400, 256, 0, stream>>>(Wg_f, Wc_f, x, coded, Bx, Bhg, Bhc, xb, h32, hb);

  pre_gemm<<<4608, 256, 0, stream>>>(xb, Bx, bg, bc, Pg, Pc);

  for (int t = 0; t < T_SEQ; ++t) {
    gate_step<<<512, 256, 0, stream>>>(hb, Bhg, Pg, u16, rhb, t);
    cand_step<<<512, 128, 0, stream>>>(rhb, Bhc, Pc, u16, h32, hb, out, t);
  }
}

// Round 3
// 734.857 us; speedup vs baseline: 1.3165x; 1.0985x over previous
//
#include <hip/hip_runtime.h>
#include <hip/hip_bf16.h>

// GRU (TF GRUCell), B=2048, T=12, D=512, H=1024, fp32 in/out.
// R7 (resubmit — R2 bench hit GPUAcquisitionTimeout, never ran):
// step kernels rebuilt m97-style like pre_gemm (R6's measured win):
// global_load_lds width-16 for A (source-XOR-swizzled, LDS linear, swizzled
// read) and B (packed lane-linear); BK=128 (8 iters, half the barriers);
// cand_step widened to 256 threads (4 waves, 16 waves/CU vs 4). nT-grouped
// XCD swizzle on steps (B-slice L2-resident, stream hb/rhb). pre_gemm/prep
// unchanged from R6 (pre_gemm at ~85% of m97-structure reference).

#define T_SEQ 12
#define BATCH 2048
#define IND 512
#define HID 1024
#define NGATE (2 * HID)  // 2048
#define NPRE (NGATE + HID)

typedef __bf16 bf16x8 __attribute__((ext_vector_type(8)));
typedef __bf16 bf16x4 __attribute__((ext_vector_type(4)));
typedef float floatx4 __attribute__((ext_vector_type(4)));

#define AS1 __attribute__((address_space(1)))
#define AS3 __attribute__((address_space(3)))

__device__ __forceinline__ void gload16(const __bf16* g, __bf16* l) {
  __builtin_amdgcn_global_load_lds((const AS1 void*)g, (AS3 void*)l, 16, 0, 0);
}

__device__ __forceinline__ float fast_sigmoid(float v) {
  v = fminf(30.f, fmaxf(-30.f, v));
  return 1.f / (1.f + __expf(-v));
}
__device__ __forceinline__ float fast_tanh(float v) {
  v = fminf(15.f, fmaxf(-15.f, v));
  float e = __expf(2.f * v);
  return (e - 1.f) / (e + 1.f);
}

// ---- fused prep: weight pack + x fp32->bf16 + h init, one dispatch ----
__global__ __launch_bounds__(256) void prep(
    const float* __restrict__ Wg, const float* __restrict__ Wc,
    const float* __restrict__ x, const float* __restrict__ coded,
    __bf16* __restrict__ Bx, __bf16* __restrict__ Bhg, __bf16* __restrict__ Bhc,
    __bf16* __restrict__ xb, float* __restrict__ h32, __bf16* __restrict__ hb) {
  int b = blockIdx.x;
  if (b < 2304) {
    int gid = b * 256 + threadIdx.x;
    int g = gid >> 6, lane = gid & 63;
    const float* W; int ld, row0, ksteps, wid; __bf16* out;
    if (g < 2048)      { W = Wg; ld = NGATE; row0 = 0;   ksteps = 16; wid = g;        out = Bx; }
    else if (g < 3072) { W = Wc; ld = HID;   row0 = 0;   ksteps = 16; wid = g - 2048; out = Bx + (size_t)2048 * 512; }
    else if (g < 7168) { W = Wg; ld = NGATE; row0 = IND; ksteps = 32; wid = g - 3072; out = Bhg; }
    else               { W = Wc; ld = HID;   row0 = IND; ksteps = 32; wid = g - 7168; out = Bhc; }
    int n16 = wid / ksteps, kt = wid - n16 * ksteps;
    int col = n16 * 16 + (lane & 15);
    int k0 = row0 + kt * 32 + (lane >> 4) * 8;
    bf16x8 v;
#pragma unroll
    for (int j = 0; j < 8; ++j) v[j] = (__bf16)W[(size_t)(k0 + j) * ld + col];
    *reinterpret_cast<bf16x8*>(out + (size_t)wid * 512 + lane * 8) = v;
  } else if (b < 4352) {
    int i = (b - 2304) * 256 + threadIdx.x;
    const float4* x4 = (const float4*)x;
    const int n4 = BATCH * T_SEQ * IND / 4;
    for (int k = i; k < n4; k += 2048 * 256) {
      float4 v = x4[k];
      bf16x4 o;
      o[0] = (__bf16)v.x; o[1] = (__bf16)v.y; o[2] = (__bf16)v.z; o[3] = (__bf16)v.w;
      *reinterpret_cast<bf16x4*>(xb + (size_t)k * 4) = o;
    }
  } else {
    int i = (b - 4352) * 256 + threadIdx.x;  // exactly BATCH*HID/4 threads
    float4 v = ((const float4*)coded)[i];
    ((float4*)h32)[i] = v;
    bf16x4 o;
    o[0] = (__bf16)v.x; o[1] = (__bf16)v.y; o[2] = (__bf16)v.z; o[3] = (__bf16)v.w;
    *reinterpret_cast<bf16x4*>(hb + (size_t)i * 4) = o;
  }
}

// ---- Px precompute: 128x128 tile, wave 64x64 (4x4 frags), K=512 ----
__global__ __launch_bounds__(256) void pre_gemm(
    const __bf16* __restrict__ xb, const __bf16* __restrict__ Bx,
    const float* __restrict__ bg, const float* __restrict__ bc,
    __bf16* __restrict__ Pg, __bf16* __restrict__ Pc) {
  __shared__ __bf16 Alds[128 * 64];  // 16 KB, linear [row][64]
  __shared__ __bf16 Blds[8192];      // 16 KB
  const int tid = threadIdx.x, lane = tid & 63, w = tid >> 6;
  const int wm = w >> 1, wn = w & 1, quad = lane >> 4, l16 = lane & 15;
  const int bid = blockIdx.x;                    // 4608 = 8 * 576
  const int wg = (bid & 7) * 576 + (bid >> 3);   // bijective XCD grouping
  const int nb = wg % 24;
  const int rest = wg / 24;
  const int mB = rest & 15;
  const int tz = rest >> 4;
  const int m0 = mB * 128;

  const __bf16* gA[4]; __bf16* lA[4];
  const __bf16* gB[4]; __bf16* lB[4];
#pragma unroll
  for (int i = 0; i < 4; ++i) {
    int c = tid + i * 256;  // [0,1024): row=c>>3 (0..127), k8=c&7
    int row = c >> 3, k8 = c & 7;
    gA[i] = xb + ((size_t)(m0 + row) * T_SEQ + tz) * IND + ((k8 ^ (row & 7)) * 8);
    lA[i] = Alds + c * 8;
    int ks2c = c >> 9, rem = c & 511;
    gB[i] = Bx + (((size_t)(nb * 8 + (rem >> 6)) * 16 + ks2c) * 64 + (rem & 63)) * 8;
    lB[i] = Blds + c * 8;
  }

  floatx4 acc[4][4] = {};
  for (int it = 0; it < 8; ++it) {
    __syncthreads();
#pragma unroll
    for (int i = 0; i < 4; ++i) gload16(gA[i] + it * 64, lA[i]);
#pragma unroll
    for (int i = 0; i < 4; ++i) gload16(gB[i] + (size_t)it * 1024, lB[i]);
    __syncthreads();
#pragma unroll
    for (int ks2 = 0; ks2 < 2; ++ks2) {
      bf16x8 af[4], bfr[4];
#pragma unroll
      for (int mf = 0; mf < 4; ++mf) {
        int row = wm * 64 + mf * 16 + l16;
        af[mf] = *(const bf16x8*)&Alds[row * 64 + (((ks2 * 4 + quad) ^ (row & 7)) * 8)];
      }
#pragma unroll
      for (int nf = 0; nf < 4; ++nf)
        bfr[nf] = *(const bf16x8*)&Blds[(ks2 * 512 + (wn * 4 + nf) * 64 + lane) * 8];
#pragma unroll
      for (int mf = 0; mf < 4; ++mf)
#pragma unroll
        for (int nf = 0; nf < 4; ++nf)
          acc[mf][nf] = __builtin_amdgcn_mfma_f32_16x16x32_bf16(af[mf], bfr[nf], acc[mf][nf], 0, 0, 0);
    }
  }

  const int n64g = nb * 2 + wn;
  const bool isg = (n64g < 32);
  __bf16* P = isg ? Pg : Pc;
  const float* bias = isg ? bg : bc;
  const int nrel = isg ? n64g : (n64g - 32);
  const int colb = nrel * 64 + l16;
#pragma unroll
  for (int mf = 0; mf < 4; ++mf) {
    int m32 = mB * 4 + wm * 2 + (mf >> 1);
    size_t tb = isg ? (((size_t)tz * 64 + m32) * 32 + n64g) * 2048
                    : (((size_t)tz * 64 + m32) * 16 + nrel) * 2048;
#pragma unroll
    for (int nf = 0; nf < 4; ++nf) {
      float bv = bias[colb + nf * 16];
      bf16x4 st;
#pragma unroll
      for (int i = 0; i < 4; ++i) st[i] = (__bf16)(acc[mf][nf][i] + bv);
      *(bf16x4*)&P[tb + (size_t)(((mf & 1) * 4 + nf) * 64 + lane) * 4] = st;
    }
  }
}

// ---- gate step: 64x128 tile, 4 waves, K=1024, BK=128, gload_lds ----
__global__ __launch_bounds__(256, 2) void gate_step(
    const __bf16* __restrict__ hb, const __bf16* __restrict__ Bhg,
    const __bf16* __restrict__ Pg, _Float16* __restrict__ u16,
    __bf16* __restrict__ rhb, int t) {
  __shared__ __bf16 Alds[64 * 128];  // 16 KB, linear [row][128]
  __shared__ __bf16 Blds[16384];     // 32 KB
  const int tid = threadIdx.x, lane = tid & 63, w = tid >> 6;
  const int wm = w >> 1, wn = w & 1, quad = lane >> 4, l16 = lane & 15;
  const int bid = blockIdx.x;                  // 512 = 8 * 64
  const int swz = (bid & 7) * 64 + (bid >> 3); // nT-grouped: B slice per XCD
  const int mT = swz & 31, nT = swz >> 5;

  const __bf16* gA[4]; __bf16* lA[4];
  const __bf16* gB[8]; __bf16* lB[8];
#pragma unroll
  for (int i = 0; i < 4; ++i) {
    int c = tid + i * 256;  // [0,1024): row=c>>4 (0..63), chunk=c&15
    int row = c >> 4, ch = c & 15;
    gA[i] = hb + (size_t)(mT * 64 + row) * HID + ((ch ^ (row & 7)) * 8);
    lA[i] = Alds + c * 8;
  }
#pragma unroll
  for (int i = 0; i < 8; ++i) {
    int c = tid + i * 256;  // [0,2048): n16rel=c>>8, rem=c&255
    gB[i] = Bhg + (size_t)(nT * 8 + (c >> 8)) * 16384 + (c & 255) * 8;
    lB[i] = Blds + c * 8;
  }

  floatx4 acc[2][4] = {};
  for (int kt = 0; kt < 8; ++kt) {
    __syncthreads();
#pragma unroll
    for (int i = 0; i < 4; ++i) gload16(gA[i] + kt * 128, lA[i]);
#pragma unroll
    for (int i = 0; i < 8; ++i) gload16(gB[i] + kt * 2048, lB[i]);
    __syncthreads();
#pragma unroll
    for (int ks2 = 0; ks2 < 4; ++ks2) {
      bf16x8 af[2], bfr[4];
#pragma unroll
      for (int mf = 0; mf < 2; ++mf) {
        int row = wm * 32 + mf * 16 + l16;
        af[mf] = *(const bf16x8*)&Alds[row * 128 + (((ks2 * 4 + quad) ^ (row & 7)) * 8)];
      }
#pragma unroll
      for (int nf = 0; nf < 4; ++nf)
        bfr[nf] = *(const bf16x8*)&Blds[(wn * 4 + nf) * 2048 + ks2 * 512 + lane * 8];
#pragma unroll
      for (int mf = 0; mf < 2; ++mf)
#pragma unroll
        for (int nf = 0; nf < 4; ++nf)
          acc[mf][nf] = __builtin_amdgcn_mfma_f32_16x16x32_bf16(af[mf], bfr[nf], acc[mf][nf], 0, 0, 0);
    }
  }

  const int m32 = mT * 2 + wm;
  const int n64 = nT * 2 + wn;
  const bool isr = (n64 < 16);
  size_t tb = (((size_t)t * 64 + m32) * 32 + n64) * 2048;
#pragma unroll
  for (int mf = 0; mf < 2; ++mf)
#pragma unroll
    for (int nf = 0; nf < 4; ++nf) {
      bf16x4 px = *(const bf16x4*)&Pg[tb + (size_t)((mf * 4 + nf) * 64 + lane) * 4];
      int col = nT * 128 + wn * 64 + nf * 16 + l16;
      int rowb = mT * 64 + wm * 32 + mf * 16 + quad * 4;
#pragma unroll
      for (int i = 0; i < 4; ++i) {
        float s = fast_sigmoid(acc[mf][nf][i] + (float)px[i]);
        if (isr) {
          size_t idx = (size_t)(rowb + i) * HID + col;
          rhb[idx] = (__bf16)(s * (float)hb[idx]);
        } else {
          u16[(size_t)(rowb + i) * HID + (col - HID)] = (_Float16)s;
        }
      }
    }
}

// ---- cand step: 64x64 tile, 4 waves (2x2 split), K=1024, BK=128 ----
__global__ __launch_bounds__(256, 2) void cand_step(
    const __bf16* __restrict__ rhb, const __bf16* __restrict__ Bhc,
    const __bf16* __restrict__ Pc, const _Float16* __restrict__ u16,
    float* __restrict__ h32, __bf16* __restrict__ hb,
    float* __restrict__ out, int t) {
  __shared__ __bf16 Alds[64 * 128];  // 16 KB
  __shared__ __bf16 Blds[8192];      // 16 KB
  const int tid = threadIdx.x, lane = tid & 63, w = tid >> 6;
  const int wm = w >> 1, wn = w & 1, quad = lane >> 4, l16 = lane & 15;
  const int bid = blockIdx.x;                  // 512 = 8 * 64
  const int swz = (bid & 7) * 64 + (bid >> 3);
  const int mT = swz & 31, nT = swz >> 5;      // nT 0..15, mT 0..31

  const __bf16* gA[4]; __bf16* lA[4];
  const __bf16* gB[4]; __bf16* lB[4];
#pragma unroll
  for (int i = 0; i < 4; ++i) {
    int c = tid + i * 256;  // [0,1024): row=c>>4, chunk=c&15
    int row = c >> 4, ch = c & 15;
    gA[i] = rhb + (size_t)(mT * 64 + row) * HID + ((ch ^ (row & 7)) * 8);
    lA[i] = Alds + c * 8;
    gB[i] = Bhc + (size_t)(nT * 4 + (c >> 8)) * 16384 + (c & 255) * 8;
    lB[i] = Blds + c * 8;
  }

  floatx4 acc[2][2] = {};
  for (int kt = 0; kt < 8; ++kt) {
    __syncthreads();
#pragma unroll
    for (int i = 0; i < 4; ++i) gload16(gA[i] + kt * 128, lA[i]);
#pragma unroll
    for (int i = 0; i < 4; ++i) gload16(gB[i] + kt * 2048, lB[i]);
    __syncthreads();
#pragma unroll
    for (int ks2 = 0; ks2 < 4; ++ks2) {
      bf16x8 af[2], bfr[2];
#pragma unroll
      for (int mf = 0; mf < 2; ++mf) {
        int row = wm * 32 + mf * 16 + l16;
        af[mf] = *(const bf16x8*)&Alds[row * 128 + (((ks2 * 4 + quad) ^ (row & 7)) * 8)];
      }
#pragma unroll
      for (int nf = 0; nf < 2; ++nf)
        bfr[nf] = *(const bf16x8*)&Blds[(wn * 2 + nf) * 2048 + ks2 * 512 + lane * 8];
#pragma unroll
      for (int mf = 0; mf < 2; ++mf)
#pragma unroll
        for (int nf = 0; nf < 2; ++nf)
          acc[mf][nf] = __builtin_amdgcn_mfma_f32_16x16x32_bf16(af[mf], bfr[nf], acc[mf][nf], 0, 0, 0);
    }
  }

  const int m32 = mT * 2 + wm;
  size_t tb = (((size_t)t * 64 + m32) * 16 + nT) * 2048;
#pragma unroll
  for (int mf = 0; mf < 2; ++mf)
#pragma unroll
    for (int nf = 0; nf < 2; ++nf) {
      bf16x4 px = *(const bf16x4*)&Pc[tb + (size_t)((mf * 4 + wn * 2 + nf) * 64 + lane) * 4];
      int col = nT * 64 + wn * 32 + nf * 16 + l16;
      int rowb = mT * 64 + wm * 32 + mf * 16 + quad * 4;
#pragma unroll
      for (int i = 0; i < 4; ++i) {
        float c = fast_tanh(acc[mf][nf][i] + (float)px[i]);
        size_t idx = (size_t)(rowb + i) * HID + col;
        float u = (float)u16[idx];
        float hnew = u * h32[idx] + (1.f - u) * c;
        h32[idx] = hnew;
        hb[idx] = (__bf16)hnew;
        __builtin_nontemporal_store(hnew, &out[(size_t)(rowb + i) * (T_SEQ * HID) + t * HID + col]);
      }
    }
}

extern "C" void kernel_launch(void* const* d_in, const int* in_sizes, int n_in,
                              void* d_out, int out_size, void* d_ws, size_t ws_size,
                              hipStream_t stream) {
  const float* x     = (const float*)d_in[0];
  const float* coded = (const float*)d_in[1];
  const float* Wg_f  = (const float*)d_in[2];
  const float* bg    = (const float*)d_in[3];
  const float* Wc_f  = (const float*)d_in[4];
  const float* bc    = (const float*)d_in[5];
  float* out = (float*)d_out;

  uintptr_t base = ((uintptr_t)d_ws + 255) & ~(uintptr_t)255;
  auto take = [&](size_t bytes) {
    void* p = (void*)base;
    base = (base + bytes + 255) & ~(uintptr_t)255;
    return p;
  };
  __bf16* Bx  = (__bf16*)take((size_t)(NPRE / 16) * 16 * 512 * 2);   // 3.1 MB
  __bf16* Bhg = (__bf16*)take((size_t)(NGATE / 16) * 32 * 512 * 2);  // 4.2 MB
  __bf16* Bhc = (__bf16*)take((size_t)(HID / 16) * 32 * 512 * 2);    // 2.1 MB
  __bf16* Pg  = (__bf16*)take((size_t)T_SEQ * 64 * 32 * 2048 * 2);   // 100.7 MB
  __bf16* Pc  = (__bf16*)take((size_t)T_SEQ * 64 * 16 * 2048 * 2);   // 50.3 MB
  __bf16* xb  = (__bf16*)take((size_t)BATCH * T_SEQ * IND * 2);      // 25.2 MB
  float*  h32 = (float*) take((size_t)BATCH * HID * 4);
  __bf16* hb  = (__bf16*)take((size_t)BATCH * HID * 2);
  _Float16* u16 = (_Float16*)take((size_t)BATCH * HID * 2);
  __bf16* rhb = (__bf16*)take((size_t)BATCH * HID * 2);

  prep<<<6400, 256, 0, stream>>>(Wg_f, Wc_f, x, coded, Bx, Bhg, Bhc, xb, h32, hb);

  pre_gemm<<<4608, 256, 0, stream>>>(xb, Bx, bg, bc, Pg, Pc);

  for (int t = 0; t < T_SEQ; ++t) {
    gate_step<<<512, 256, 0, stream>>>(hb, Bhg, Pg, u16, rhb, t);
    cand_step<<<512, 256, 0, stream>>>(rhb, Bhc, Pc, u16, h32, hb, out, t);
  }
}

// Round 5
// 716.802 us; speedup vs baseline: 1.3496x; 1.0252x over previous
//
#include <hip/hip_runtime.h>
#include <hip/hip_bf16.h>

// GRU (TF GRUCell), B=2048, T=12, D=512, H=1024, fp32 in/out.
// R8 (resubmit #2 — broker timeout both attempts; never executed):
// single persistent step kernel (512 blocks x 12 steps) replacing 24
// dispatches. All recurrence dependencies are mT-local (per-batch-slice), so
// sync is per-16-block-group flag counters, placed same-XCD via bid%8.
// Mutable cross-block reads use sc0 (aux=1) global_load_lds (L1 bypass, L2 =
// XCD coherence point). u-gate stays in LDS (block-local, u16 buffer gone);
// r*h operand snapped from staged A-tile in LDS. No grid sync, no cache-
// flushing fences. prep/pre_gemm unchanged from R6 (measured 102 us, MfmaUtil 33).

#define T_SEQ 12
#define BATCH 2048
#define IND 512
#define HID 1024
#define NGATE (2 * HID)  // 2048
#define NPRE (NGATE + HID)

typedef __bf16 bf16x8 __attribute__((ext_vector_type(8)));
typedef __bf16 bf16x4 __attribute__((ext_vector_type(4)));
typedef float floatx4 __attribute__((ext_vector_type(4)));

#define AS1 __attribute__((address_space(1)))
#define AS3 __attribute__((address_space(3)))

__device__ __forceinline__ void gload16(const __bf16* g, __bf16* l) {
  __builtin_amdgcn_global_load_lds((const AS1 void*)g, (AS3 void*)l, 16, 0, 0);
}
// sc0 (L1-bypass) variant: for buffers mutated by other blocks on this XCD.
__device__ __forceinline__ void gload16c(const __bf16* g, __bf16* l) {
  __builtin_amdgcn_global_load_lds((const AS1 void*)g, (AS3 void*)l, 16, 0, 1);
}

__device__ __forceinline__ float fast_sigmoid(float v) {
  v = fminf(30.f, fmaxf(-30.f, v));
  return 1.f / (1.f + __expf(-v));
}
__device__ __forceinline__ float fast_tanh(float v) {
  v = fminf(15.f, fmaxf(-15.f, v));
  float e = __expf(2.f * v);
  return (e - 1.f) / (e + 1.f);
}

// ---- fused prep: weight pack + x fp32->bf16 + h init + ctr zero ----
__global__ __launch_bounds__(256) void prep(
    const float* __restrict__ Wg, const float* __restrict__ Wc,
    const float* __restrict__ x, const float* __restrict__ coded,
    __bf16* __restrict__ Bx, __bf16* __restrict__ Bhg, __bf16* __restrict__ Bhc,
    __bf16* __restrict__ xb, float* __restrict__ h32, __bf16* __restrict__ hb,
    unsigned* __restrict__ ctr) {
  int b = blockIdx.x;
  if (b < 2304) {
    int gid = b * 256 + threadIdx.x;
    int g = gid >> 6, lane = gid & 63;
    const float* W; int ld, row0, ksteps, wid; __bf16* out;
    if (g < 2048)      { W = Wg; ld = NGATE; row0 = 0;   ksteps = 16; wid = g;        out = Bx; }
    else if (g < 3072) { W = Wc; ld = HID;   row0 = 0;   ksteps = 16; wid = g - 2048; out = Bx + (size_t)2048 * 512; }
    else if (g < 7168) { W = Wg; ld = NGATE; row0 = IND; ksteps = 32; wid = g - 3072; out = Bhg; }
    else               { W = Wc; ld = HID;   row0 = IND; ksteps = 32; wid = g - 7168; out = Bhc; }
    int n16 = wid / ksteps, kt = wid - n16 * ksteps;
    int col = n16 * 16 + (lane & 15);
    int k0 = row0 + kt * 32 + (lane >> 4) * 8;
    bf16x8 v;
#pragma unroll
    for (int j = 0; j < 8; ++j) v[j] = (__bf16)W[(size_t)(k0 + j) * ld + col];
    *reinterpret_cast<bf16x8*>(out + (size_t)wid * 512 + lane * 8) = v;
  } else if (b < 4352) {
    int i = (b - 2304) * 256 + threadIdx.x;
    const float4* x4 = (const float4*)x;
    const int n4 = BATCH * T_SEQ * IND / 4;
    for (int k = i; k < n4; k += 2048 * 256) {
      float4 v = x4[k];
      bf16x4 o;
      o[0] = (__bf16)v.x; o[1] = (__bf16)v.y; o[2] = (__bf16)v.z; o[3] = (__bf16)v.w;
      *reinterpret_cast<bf16x4*>(xb + (size_t)k * 4) = o;
    }
  } else {
    int i = (b - 4352) * 256 + threadIdx.x;  // exactly BATCH*HID/4 threads
    if (b == 4352) {
#pragma unroll
      for (int j = 0; j < 4; ++j) ctr[threadIdx.x + j * 256] = 0u;
    }
    float4 v = ((const float4*)coded)[i];
    ((float4*)h32)[i] = v;
    bf16x4 o;
    o[0] = (__bf16)v.x; o[1] = (__bf16)v.y; o[2] = (__bf16)v.z; o[3] = (__bf16)v.w;
    *reinterpret_cast<bf16x4*>(hb + (size_t)i * 4) = o;
  }
}

// ---- Px precompute: 128x128 tile, wave 64x64 (4x4 frags), K=512 ----
__global__ __launch_bounds__(256) void pre_gemm(
    const __bf16* __restrict__ xb, const __bf16* __restrict__ Bx,
    const float* __restrict__ bg, const float* __restrict__ bc,
    __bf16* __restrict__ Pg, __bf16* __restrict__ Pc) {
  __shared__ __bf16 Alds[128 * 64];  // 16 KB, linear [row][64]
  __shared__ __bf16 Blds[8192];      // 16 KB
  const int tid = threadIdx.x, lane = tid & 63, w = tid >> 6;
  const int wm = w >> 1, wn = w & 1, quad = lane >> 4, l16 = lane & 15;
  const int bid = blockIdx.x;                    // 4608 = 8 * 576
  const int wg = (bid & 7) * 576 + (bid >> 3);   // bijective XCD grouping
  const int nb = wg % 24;
  const int rest = wg / 24;
  const int mB = rest & 15;
  const int tz = rest >> 4;
  const int m0 = mB * 128;

  const __bf16* gA[4]; __bf16* lA[4];
  const __bf16* gB[4]; __bf16* lB[4];
#pragma unroll
  for (int i = 0; i < 4; ++i) {
    int c = tid + i * 256;  // [0,1024): row=c>>3 (0..127), k8=c&7
    int row = c >> 3, k8 = c & 7;
    gA[i] = xb + ((size_t)(m0 + row) * T_SEQ + tz) * IND + ((k8 ^ (row & 7)) * 8);
    lA[i] = Alds + c * 8;
    int ks2c = c >> 9, rem = c & 511;
    gB[i] = Bx + (((size_t)(nb * 8 + (rem >> 6)) * 16 + ks2c) * 64 + (rem & 63)) * 8;
    lB[i] = Blds + c * 8;
  }

  floatx4 acc[4][4] = {};
  for (int it = 0; it < 8; ++it) {
    __syncthreads();
#pragma unroll
    for (int i = 0; i < 4; ++i) gload16(gA[i] + it * 64, lA[i]);
#pragma unroll
    for (int i = 0; i < 4; ++i) gload16(gB[i] + (size_t)it * 1024, lB[i]);
    __syncthreads();
#pragma unroll
    for (int ks2 = 0; ks2 < 2; ++ks2) {
      bf16x8 af[4], bfr[4];
#pragma unroll
      for (int mf = 0; mf < 4; ++mf) {
        int row = wm * 64 + mf * 16 + l16;
        af[mf] = *(const bf16x8*)&Alds[row * 64 + (((ks2 * 4 + quad) ^ (row & 7)) * 8)];
      }
#pragma unroll
      for (int nf = 0; nf < 4; ++nf)
        bfr[nf] = *(const bf16x8*)&Blds[(ks2 * 512 + (wn * 4 + nf) * 64 + lane) * 8];
#pragma unroll
      for (int mf = 0; mf < 4; ++mf)
#pragma unroll
        for (int nf = 0; nf < 4; ++nf)
          acc[mf][nf] = __builtin_amdgcn_mfma_f32_16x16x32_bf16(af[mf], bfr[nf], acc[mf][nf], 0, 0, 0);
    }
  }

  const int n64g = nb * 2 + wn;
  const bool isg = (n64g < 32);
  __bf16* P = isg ? Pg : Pc;
  const float* bias = isg ? bg : bc;
  const int nrel = isg ? n64g : (n64g - 32);
  const int colb = nrel * 64 + l16;
#pragma unroll
  for (int mf = 0; mf < 4; ++mf) {
    int m32 = mB * 4 + wm * 2 + (mf >> 1);
    size_t tb = isg ? (((size_t)tz * 64 + m32) * 32 + n64g) * 2048
                    : (((size_t)tz * 64 + m32) * 16 + nrel) * 2048;
#pragma unroll
    for (int nf = 0; nf < 4; ++nf) {
      float bv = bias[colb + nf * 16];
      bf16x4 st;
#pragma unroll
      for (int i = 0; i < 4; ++i) st[i] = (__bf16)(acc[mf][nf][i] + bv);
      *(bf16x4*)&P[tb + (size_t)(((mf & 1) * 4 + nf) * 64 + lane) * 4] = st;
    }
  }
}

// ---- persistent GRU steps: 512 blocks, 12 t, per-mT-group flag sync ----
// block bid: mT = (bid&7)*4 + ((bid>>3)&3)  (16 blocks per mT, all bid%8 equal
// -> same XCD under round-robin dispatch); sub = bid>>5 in [0,16).
// Gate phase: 64x128 tile = r-cols [sub*64,+64) U u-cols [1024+sub*64,+64).
// u stays in LDS for this block's own cand phase. Cand phase: 64x64 tile at
// cols [sub*64,+64). Sync: relaxed agent atomics; release via __syncthreads'
// vmcnt(0) drain; mutable consumes via sc0 loads (L2 is the coherence point).
__global__ __launch_bounds__(256, 2) void gru_steps(
    const __bf16* __restrict__ Bhg, const __bf16* __restrict__ Bhc,
    const __bf16* __restrict__ Pg, const __bf16* __restrict__ Pc,
    float* __restrict__ h32, __bf16* __restrict__ hb,
    __bf16* __restrict__ rhb, float* __restrict__ out,
    unsigned* __restrict__ ctr) {
  __shared__ __bf16 Alds[64 * 128];  // 16 KB
  __shared__ __bf16 Blds[16384];     // 32 KB; [8192:] doubles as u-tile (fp32)
  float* uS = (float*)&Blds[8192];   // 64x64 fp32, live gate-epi -> cand-epi
  const int tid = threadIdx.x, lane = tid & 63, w = tid >> 6;
  const int wm = w >> 1, wn = w & 1, quad = lane >> 4, l16 = lane & 15;
  const int bid = blockIdx.x;
  const int mT = (bid & 7) * 4 + ((bid >> 3) & 3);
  const int sub = bid >> 5;
  unsigned* cG = ctr + mT * 16;
  unsigned* cC = ctr + 512 + mT * 16;

  int offA[4];  // A-staging source offsets (same geometry for hb and rhb)
#pragma unroll
  for (int i = 0; i < 4; ++i) {
    int c = tid + i * 256, row = c >> 4, ch = c & 15;
    offA[i] = (mT * 64 + row) * HID + ((ch ^ (row & 7)) * 8);
  }

  for (int t = 0; t < T_SEQ; ++t) {
    // ================= GATE =================
    {
      floatx4 acc[2][4] = {};
      __bf16 hr[2][4][4];
      for (int kt = 0; kt < 8; ++kt) {
        __syncthreads();
#pragma unroll
        for (int i = 0; i < 4; ++i)
          gload16c(hb + offA[i] + kt * 128, Alds + (tid + i * 256) * 8);
#pragma unroll
        for (int i = 0; i < 8; ++i) {
          int gidx = (i < 4) ? (sub * 4 + i) : (64 + sub * 4 + (i - 4));
          gload16(Bhg + (size_t)gidx * 16384 + kt * 2048 + tid * 8,
                  Blds + (tid + i * 256) * 8);
        }
        __syncthreads();
#pragma unroll
        for (int ks2 = 0; ks2 < 4; ++ks2) {
          bf16x8 af[2], bfr[4];
#pragma unroll
          for (int mf = 0; mf < 2; ++mf) {
            int row = wm * 32 + mf * 16 + l16;
            af[mf] = *(const bf16x8*)&Alds[row * 128 + (((ks2 * 4 + quad) ^ (row & 7)) * 8)];
          }
#pragma unroll
          for (int nf = 0; nf < 4; ++nf)
            bfr[nf] = *(const bf16x8*)&Blds[(wn * 4 + nf) * 2048 + ks2 * 512 + lane * 8];
#pragma unroll
          for (int mf = 0; mf < 2; ++mf)
#pragma unroll
            for (int nf = 0; nf < 4; ++nf)
              acc[mf][nf] = __builtin_amdgcn_mfma_f32_16x16x32_bf16(af[mf], bfr[nf], acc[mf][nf], 0, 0, 0);
        }
        // snapshot h (bf16) for the r*h product while its cols are in LDS
        if (kt == (sub >> 1) && wn == 0) {
#pragma unroll
          for (int mf = 0; mf < 2; ++mf)
#pragma unroll
            for (int nf = 0; nf < 4; ++nf)
#pragma unroll
              for (int i = 0; i < 4; ++i) {
                int r = wm * 32 + mf * 16 + quad * 4 + i;
                int c = (sub & 1) * 64 + nf * 16 + l16;
                hr[mf][nf][i] = Alds[r * 128 + (((c >> 3) ^ (r & 7)) * 8) + (c & 7)];
              }
        }
      }
      const int n64 = wn * 16 + sub;  // wn=0 -> r block, wn=1 -> u block
      const int m32 = mT * 2 + wm;
      size_t tb = (((size_t)t * 64 + m32) * 32 + n64) * 2048;
#pragma unroll
      for (int mf = 0; mf < 2; ++mf)
#pragma unroll
        for (int nf = 0; nf < 4; ++nf) {
          bf16x4 px = *(const bf16x4*)&Pg[tb + (size_t)((mf * 4 + nf) * 64 + lane) * 4];
          int rowb = mT * 64 + wm * 32 + mf * 16 + quad * 4;
#pragma unroll
          for (int i = 0; i < 4; ++i) {
            float s = fast_sigmoid(acc[mf][nf][i] + (float)px[i]);
            if (wn == 0) {
              rhb[(size_t)(rowb + i) * HID + sub * 64 + nf * 16 + l16] =
                  (__bf16)(s * (float)hr[mf][nf][i]);
            } else {
              uS[(wm * 32 + mf * 16 + quad * 4 + i) * 64 + nf * 16 + l16] = s;
            }
          }
        }
    }
    __syncthreads();  // drains all waves' stores (vmcnt 0) + uS visible
    if (tid == 0) {
      __hip_atomic_fetch_add(cG, 1u, __ATOMIC_RELAXED, __HIP_MEMORY_SCOPE_AGENT);
      unsigned tgt = 16u * (t + 1);
      while (__hip_atomic_load(cG, __ATOMIC_RELAXED, __HIP_MEMORY_SCOPE_AGENT) < tgt)
        __builtin_amdgcn_s_sleep(2);
    }
    __syncthreads();
    // ================= CAND =================
    {
      floatx4 acc[2][2] = {};
      for (int kt = 0; kt < 8; ++kt) {
        __syncthreads();
#pragma unroll
        for (int i = 0; i < 4; ++i)
          gload16c(rhb + offA[i] + kt * 128, Alds + (tid + i * 256) * 8);
#pragma unroll
        for (int i = 0; i < 4; ++i)
          gload16(Bhc + (size_t)(sub * 4 + i) * 16384 + kt * 2048 + tid * 8,
                  Blds + (tid + i * 256) * 8);
        __syncthreads();
#pragma unroll
        for (int ks2 = 0; ks2 < 4; ++ks2) {
          bf16x8 af[2], bfr[2];
#pragma unroll
          for (int mf = 0; mf < 2; ++mf) {
            int row = wm * 32 + mf * 16 + l16;
            af[mf] = *(const bf16x8*)&Alds[row * 128 + (((ks2 * 4 + quad) ^ (row & 7)) * 8)];
          }
#pragma unroll
          for (int nf = 0; nf < 2; ++nf)
            bfr[nf] = *(const bf16x8*)&Blds[(wn * 2 + nf) * 2048 + ks2 * 512 + lane * 8];
#pragma unroll
          for (int mf = 0; mf < 2; ++mf)
#pragma unroll
            for (int nf = 0; nf < 2; ++nf)
              acc[mf][nf] = __builtin_amdgcn_mfma_f32_16x16x32_bf16(af[mf], bfr[nf], acc[mf][nf], 0, 0, 0);
        }
      }
      const int m32 = mT * 2 + wm;
      size_t tb = (((size_t)t * 64 + m32) * 16 + sub) * 2048;
#pragma unroll
      for (int mf = 0; mf < 2; ++mf)
#pragma unroll
        for (int nf = 0; nf < 2; ++nf) {
          bf16x4 px = *(const bf16x4*)&Pc[tb + (size_t)((mf * 4 + wn * 2 + nf) * 64 + lane) * 4];
          int col = sub * 64 + wn * 32 + nf * 16 + l16;
          int rowb = mT * 64 + wm * 32 + mf * 16 + quad * 4;
#pragma unroll
          for (int i = 0; i < 4; ++i) {
            float c = fast_tanh(acc[mf][nf][i] + (float)px[i]);
            size_t idx = (size_t)(rowb + i) * HID + col;
            float u = uS[(wm * 32 + mf * 16 + quad * 4 + i) * 64 + wn * 32 + nf * 16 + l16];
            float hnew = u * h32[idx] + (1.f - u) * c;
            h32[idx] = hnew;
            hb[idx] = (__bf16)hnew;
            __builtin_nontemporal_store(hnew, &out[(size_t)(rowb + i) * (T_SEQ * HID) + t * HID + col]);
          }
        }
    }
    __syncthreads();
    if (tid == 0) {
      __hip_atomic_fetch_add(cC, 1u, __ATOMIC_RELAXED, __HIP_MEMORY_SCOPE_AGENT);
      unsigned tgt = 16u * (t + 1);
      while (__hip_atomic_load(cC, __ATOMIC_RELAXED, __HIP_MEMORY_SCOPE_AGENT) < tgt)
        __builtin_amdgcn_s_sleep(2);
    }
    __syncthreads();
  }
}

extern "C" void kernel_launch(void* const* d_in, const int* in_sizes, int n_in,
                              void* d_out, int out_size, void* d_ws, size_t ws_size,
                              hipStream_t stream) {
  const float* x     = (const float*)d_in[0];
  const float* coded = (const float*)d_in[1];
  const float* Wg_f  = (const float*)d_in[2];
  const float* bg    = (const float*)d_in[3];
  const float* Wc_f  = (const float*)d_in[4];
  const float* bc    = (const float*)d_in[5];
  float* out = (float*)d_out;

  uintptr_t base = ((uintptr_t)d_ws + 255) & ~(uintptr_t)255;
  auto take = [&](size_t bytes) {
    void* p = (void*)base;
    base = (base + bytes + 255) & ~(uintptr_t)255;
    return p;
  };
  __bf16* Bx  = (__bf16*)take((size_t)(NPRE / 16) * 16 * 512 * 2);   // 3.1 MB
  __bf16* Bhg = (__bf16*)take((size_t)(NGATE / 16) * 32 * 512 * 2);  // 4.2 MB
  __bf16* Bhc = (__bf16*)take((size_t)(HID / 16) * 32 * 512 * 2);    // 2.1 MB
  __bf16* Pg  = (__bf16*)take((size_t)T_SEQ * 64 * 32 * 2048 * 2);   // 100.7 MB
  __bf16* Pc  = (__bf16*)take((size_t)T_SEQ * 64 * 16 * 2048 * 2);   // 50.3 MB
  __bf16* xb  = (__bf16*)take((size_t)BATCH * T_SEQ * IND * 2);      // 25.2 MB
  float*  h32 = (float*) take((size_t)BATCH * HID * 4);
  __bf16* hb  = (__bf16*)take((size_t)BATCH * HID * 2);
  __bf16* rhb = (__bf16*)take((size_t)BATCH * HID * 2);
  unsigned* ctr = (unsigned*)take(1024 * sizeof(unsigned));

  prep<<<6400, 256, 0, stream>>>(Wg_f, Wc_f, x, coded, Bx, Bhg, Bhc, xb, h32, hb, ctr);

  pre_gemm<<<4608, 256, 0, stream>>>(xb, Bx, bg, bc, Pg, Pc);

  gru_steps<<<512, 256, 0, stream>>>(Bhg, Bhc, Pg, Pc, h32, hb, rhb, out, ctr);
}